// Round 18
// baseline (203.192 us; speedup 1.0000x reference)
//
#include <hip/hip_runtime.h>
#include <cfloat>

#define PIXB 1024
static const size_t OFF_Z = 6291456;   // recon = 32*3*256*256
static const size_t OFF_E = 23068672;  // OFF_Z + 32*512*32*32
static const size_t OFF_A = 39845888;  // OFF_E + 32*512*32*32

typedef __attribute__((address_space(1))) const unsigned int cg_u32;
typedef __attribute__((address_space(3))) unsigned int l_u32;
typedef _Float16 f16x8 __attribute__((ext_vector_type(8)));
typedef _Float16 f16x4 __attribute__((ext_vector_type(4)));
typedef float f32x16 __attribute__((ext_vector_type(16)));

#define SPLIT_SCALE 4096.0f
#define SPLIT_INV   (1.0f / 4096.0f)

#define GL16(srcp, dstp) __builtin_amdgcn_global_load_lds((cg_u32*)(srcp), (l_u32*)(dstp), 16, 0, 0)

// ---------------- prep: all weight-side tables ------------------------------
// wq (single-table kslot-major), strides in HALVES:
//   off = ch*32768 + spl*16384 + kslot*4096 + code*8   (1MB total)
__global__ __launch_bounds__(256) void k_prep(const float* __restrict__ W,
                                              const float* __restrict__ dw,
                                              const float* __restrict__ ew,
                                              _Float16* __restrict__ wq,
                                              float* __restrict__ w2,
                                              _Float16* __restrict__ aq,
                                              _Float16* __restrict__ wrow,
                                              _Float16* __restrict__ dwh,
                                              int do_aux) {
  const int t = threadIdx.x;
  const int bx = blockIdx.x;
  __shared__ float T[64][65];
  __shared__ float T2[128][65];
  if (bx < 32) {
    __shared__ float TS[32][260];
    const int cp = bx >> 4, ch = bx & 15;
#pragma unroll
    for (int i = 0; i < 32; ++i)
      TS[i][t] = W[(size_t)(ch * 32 + i) * 512 + cp * 256 + t];
    __syncthreads();
#pragma unroll
    for (int j = 0; j < 4; ++j) {
      const int u = j * 256 + t;
      const int cl = u >> 2, kslot = u & 3;
      f16x8 h, l;
#pragma unroll
      for (int jj = 0; jj < 8; ++jj) {
        const float v = TS[kslot * 8 + jj][cl];
        const _Float16 hh = (_Float16)v;
        h[jj] = hh;
        l[jj] = (_Float16)((v - (float)hh) * SPLIT_SCALE);
      }
      _Float16* base = wq + ch * 32768 + kslot * 4096 + (cp * 256 + cl) * 8;
      *(f16x8*)(base) = h;             // spl 0
      *(f16x8*)(base + 16384) = l;     // spl 1
    }
    return;
  }
  if (bx < 34) {
    const int k = (bx - 32) * 256 + t;
    float acc = 0.f;
    for (int d = 0; d < 512; ++d) { const float v = W[(size_t)d * 512 + k]; acc = fmaf(v, v, acc); }
    w2[k] = acc;
    return;
  }
  if (bx < 46) {                 // aq: enc_w [c][192] -> chunk images (unchanged)
    const int ch = bx - 34;
#pragma unroll
    for (int cc = 0; cc < 2; ++cc) {
      const int c = cc * 256 + t;
      const float* src = ew + (size_t)c * 192 + ch * 16;
#pragma unroll
      for (int slot = 0; slot < 2; ++slot) {
        f16x8 h, l;
#pragma unroll
        for (int j = 0; j < 8; ++j) {
          const float v = src[slot * 8 + j];
          const _Float16 hh = (_Float16)v;
          h[j] = hh;
          l[j] = (_Float16)((v - (float)hh) * SPLIT_SCALE);
        }
        const int se = slot ^ ((c >> 2) & 1);
        _Float16* dst = aq + (size_t)ch * 16384 + c * 16 + se * 8;
        *(f16x8*)dst = h;
        *(f16x8*)(dst + 8192) = l;
      }
    }
    return;
  }
  if (!do_aux) return;
  if (bx < 110) {                // wrow: transpose W [d][c] -> fp16 [c][d]
    const int id = bx - 46;
    const int c0 = (id & 7) * 64, d0 = (id >> 3) * 64;
#pragma unroll
    for (int i = 0; i < 16; ++i) {
      const int dl = i * 4 + (t >> 6);
      T[dl][t & 63] = W[(size_t)(d0 + dl) * 512 + c0 + (t & 63)];
    }
    __syncthreads();
#pragma unroll
    for (int i = 0; i < 16; ++i) {
      const int cl = i * 4 + (t >> 6);
      const int dl = t & 63;
      wrow[(size_t)(c0 + cl) * 512 + d0 + dl] = (_Float16)T[dl][cl];
    }
    return;
  }
  {                              // dwh: transpose dec_w [d][m] -> fp16 [m][d]
    const int id = bx - 110;
    const int m0 = (id % 3) * 64, d0 = (id / 3) * 128;
#pragma unroll
    for (int i = 0; i < 32; ++i) {
      const int idx = i * 256 + t;
      const int dl = idx >> 6, ml = idx & 63;
      T2[dl][ml] = dw[(size_t)(d0 + dl) * 192 + m0 + ml];
    }
    __syncthreads();
#pragma unroll
    for (int i = 0; i < 32; ++i) {
      const int idx = i * 256 + t;
      const int ml = idx >> 7, dl = idx & 127;
      dwh[(size_t)(m0 + ml) * 512 + d0 + dl] = (_Float16)T2[dl][ml];
    }
  }
}

// -------- FUSED encode + distance + argmin + gather -------------------------
// Round 17 + the REAL fix: dist phase covers 4 code-tiles per wave (ct2 0..3,
// codes wc*128 + ct2*32 + row -> full 0..511). Rounds 16/17 only iterated
// ct2 0..1 -> half the codebook never scored -> argmin garbage. Acc budget
// 128 AGPR (dA[4]+dB[4]) = same as passing rounds 5-7 (no spill at 2 w/SIMD).
__global__ __launch_bounds__(512) void k_fused(const float* __restrict__ x,
                                               const _Float16* __restrict__ aq,
                                               const _Float16* __restrict__ wq,
                                               const float* __restrict__ eb,
                                               const float* __restrict__ w2ws,
                                               const float* __restrict__ Wc,
                                               float* __restrict__ out) {
  __shared__ __align__(16) unsigned char CB[131072];  // encode: A 3x32K | B 4x8K ; dist: z-split 128K
  __shared__ float ebL[512];
  __shared__ float WV[512];
  __shared__ int   WI[512];
  __shared__ int   IDX[64];
  const int t = threadIdx.x;
  ebL[t] = eb[t];
  const int w = t >> 6, lane = t & 63;
  const int wc = w & 3, wp = w >> 2;
  const int n0 = blockIdx.x * 64;
  const int b = n0 >> 10, pixbase = n0 & 1023;
  const int i0 = pixbase >> 5;
  const int row = lane & 31, hi = lane >> 5;
  const int pl = wp * 32 + row;

  // ================= encode phase (identical to r12-15) =================
  int ab[4];
#pragma unroll
  for (int ct = 0; ct < 4; ++ct) {
    const int c = wc * 128 + ct * 32 + row;
    ab[ct] = c * 32 + ((hi ^ ((c >> 2) & 1)) << 4);
  }
  const int u = t & 255, srow = u >> 6, vsl = u & 63;
  const int csrc = vsl ^ ((vsl >> 3) & 1);
  const float* xb = x + ((size_t)b * 3 * 256 + (i0 + (srow >> 1)) * 8 + (srow & 1)) * 256 + csrc * 4;
  const int bv0 = (((2 * row) ^ ((row >> 2) & 1)) << 4);
  const int bv1 = (((2 * row + 1) ^ ((row >> 2) & 1)) << 4);
  const int brb = wp * 4096 + (wp * 2 + hi) * 1024;

  f32x16 accA[4], accB[4];
#pragma unroll
  for (int ct = 0; ct < 4; ++ct) { accA[ct] = (f32x16)(0.0f); accB[ct] = (f32x16)(0.0f); }

#define STAGE_A(chv) { const _Float16* as_ = aq + (size_t)(chv) * 16384 + t * 8;            \
    char* ad_ = (char*)CB + ((chv) % 3) * 32768 + t * 16;                                   \
    GL16(as_, ad_); GL16(as_ + 4096, ad_ + 8192);                                           \
    GL16(as_ + 8192, ad_ + 16384); GL16(as_ + 12288, ad_ + 24576); }
#define STAGE_B(chv) GL16(xb + (((chv) >> 2) * 65536 + ((chv) & 3) * 512),                  \
                          (char*)CB + 98304 + (((chv) & 3)) * 8192 + t * 16)
#define ECOMP(chv)                                                                          \
  { const char* abuf = (const char*)CB + ((chv) % 3) * 32768;                               \
    const char* bbuf = (const char*)CB + 98304 + ((chv) & 3) * 8192 + brb;                  \
    const float4 xa = *(const float4*)(bbuf + bv0);                                         \
    const float4 xc = *(const float4*)(bbuf + bv1);                                         \
    const float xs[8] = {xa.x, xa.y, xa.z, xa.w, xc.x, xc.y, xc.z, xc.w};                   \
    f16x8 Bh, Bl;                                                                           \
    _Pragma("unroll") for (int q = 0; q < 8; ++q) {                                         \
      const _Float16 hh = (_Float16)xs[q];                                                  \
      Bh[q] = hh; Bl[q] = (_Float16)((xs[q] - (float)hh) * SPLIT_SCALE); }                  \
    __builtin_amdgcn_s_setprio(1);                                                          \
    _Pragma("unroll") for (int ct_ = 0; ct_ < 4; ++ct_) {                                   \
      const f16x8 Ah = *(const f16x8*)(abuf + ab[ct_]);                                     \
      const f16x8 Al = *(const f16x8*)(abuf + 16384 + ab[ct_]);                             \
      accA[ct_] = __builtin_amdgcn_mfma_f32_32x32x16_f16(Ah, Bh, accA[ct_], 0, 0, 0);       \
      accB[ct_] = __builtin_amdgcn_mfma_f32_32x32x16_f16(Ah, Bl, accB[ct_], 0, 0, 0);       \
      accB[ct_] = __builtin_amdgcn_mfma_f32_32x32x16_f16(Al, Bh, accB[ct_], 0, 0, 0); }     \
    __builtin_amdgcn_s_setprio(0); }
#define EPHASE(chv, waitlit)                                                                \
  { asm volatile("s_waitcnt vmcnt(" #waitlit ")" ::: "memory");                             \
    __builtin_amdgcn_sched_barrier(0);                                                      \
    __builtin_amdgcn_s_barrier();                                                           \
    ECOMP(chv);                                                                             \
    __builtin_amdgcn_s_barrier(); }

  STAGE_A(0); STAGE_B(0);
  STAGE_A(1); STAGE_B(1);
  STAGE_B(2);
#pragma unroll 1
  for (int ch = 0; ch < 9; ++ch) {
    STAGE_A(ch + 2);
    STAGE_B(ch + 3);
    EPHASE(ch, 11);
  }
  STAGE_A(11);
  EPHASE(9, 10);
  EPHASE(10, 5);
  EPHASE(11, 0);
#undef STAGE_A
#undef STAGE_B
#undef ECOMP
#undef EPHASE

  // ===== epilogue: z_e store + fp16-split into LDS z-buffer =====
  // z-buffer (bytes): chz*8192 + spl*4096 + kslot*1024 + pix*16 (+hi*8)
#pragma unroll
  for (int ct = 0; ct < 4; ++ct) {
    float zv[16];
#pragma unroll
    for (int r = 0; r < 16; ++r) {
      const int c = wc * 128 + ct * 32 + (r & 3) + ((r >> 2) << 3) + (hi << 2);
      zv[r] = fmaf(accB[ct][r], SPLIT_INV, accA[ct][r]) + ebL[c];
      out[OFF_Z + ((size_t)(b * 512 + c)) * 1024 + pixbase + pl] = zv[r];
    }
    const int chz = wc * 4 + ct;
#pragma unroll
    for (int ks = 0; ks < 4; ++ks) {
      f16x4 hv, lv;
#pragma unroll
      for (int q = 0; q < 4; ++q) {
        const float f = zv[ks * 4 + q];
        const _Float16 hh = (_Float16)f;
        hv[q] = hh;
        lv[q] = (_Float16)((f - (float)hh) * SPLIT_SCALE);
      }
      char* dst = (char*)CB + chz * 8192 + ks * 1024 + pl * 16 + hi * 8;
      *(f16x4*)dst = hv;
      *(f16x4*)(dst + 4096) = lv;
    }
  }
  __syncthreads();

  // ================= distance phase: barrier-free, W reg-streamed ==========
  // 4 code tiles per wave (FULL coverage): codes wc*128 + ct2*32 + row,
  // ct2 = 0..3. A from global (coalesced 16B, L2-hot); B from LDS z-buffer.
  // wq strides (halves): ch*32768, spl +16384, kslot*4096, code*8.
  f32x16 dA[4], dB[4];
#pragma unroll
  for (int ct2 = 0; ct2 < 4; ++ct2) { dA[ct2] = (f32x16)(0.0f); dB[ct2] = (f32x16)(0.0f); }
  const _Float16* wbase = wq + (size_t)(wc * 128 + row) * 8 + hi * 4096;

#pragma unroll
  for (int ch = 0; ch < 16; ++ch) {
    const char* zbc = (const char*)CB + ch * 8192;
    const f16x8 Bh0 = *(const f16x8*)(zbc + hi * 1024 + pl * 16);
    const f16x8 Bh1 = *(const f16x8*)(zbc + (2 + hi) * 1024 + pl * 16);
    const f16x8 Bl0 = *(const f16x8*)(zbc + 4096 + hi * 1024 + pl * 16);
    const f16x8 Bl1 = *(const f16x8*)(zbc + 4096 + (2 + hi) * 1024 + pl * 16);
#pragma unroll
    for (int ct2 = 0; ct2 < 4; ++ct2) {
      const _Float16* wpp = wbase + ch * 32768 + ct2 * 256;
      const f16x8 Ah0 = *(const f16x8*)(wpp);                 // spl0, kslot hi
      const f16x8 Ah1 = *(const f16x8*)(wpp + 8192);          // spl0, kslot 2+hi
      const f16x8 Al0 = *(const f16x8*)(wpp + 16384);         // spl1, kslot hi
      const f16x8 Al1 = *(const f16x8*)(wpp + 24576);         // spl1, kslot 2+hi
      dA[ct2] = __builtin_amdgcn_mfma_f32_32x32x16_f16(Ah0, Bh0, dA[ct2], 0, 0, 0);
      dB[ct2] = __builtin_amdgcn_mfma_f32_32x32x16_f16(Ah0, Bl0, dB[ct2], 0, 0, 0);
      dB[ct2] = __builtin_amdgcn_mfma_f32_32x32x16_f16(Al0, Bh0, dB[ct2], 0, 0, 0);
      dA[ct2] = __builtin_amdgcn_mfma_f32_32x32x16_f16(Ah1, Bh1, dA[ct2], 0, 0, 0);
      dB[ct2] = __builtin_amdgcn_mfma_f32_32x32x16_f16(Ah1, Bl1, dB[ct2], 0, 0, 0);
      dB[ct2] = __builtin_amdgcn_mfma_f32_32x32x16_f16(Al1, Bh1, dB[ct2], 0, 0, 0);
    }
  }

  // ---- d2 + per-thread argmin over this thread's 64 codes ----
  float bv = FLT_MAX; int bi = 0x7fffffff;
#pragma unroll
  for (int ct2 = 0; ct2 < 4; ++ct2) {
#pragma unroll
    for (int r = 0; r < 16; ++r) {
      const int code = wc * 128 + ct2 * 32 + ((r & 3) + ((r >> 2) << 3) + (hi << 2));
      const float zw = fmaf(dB[ct2][r], SPLIT_INV, dA[ct2][r]);
      const float d2 = fmaf(-2.f, zw, w2ws[code]);
      if (d2 < bv || (d2 == bv && code < bi)) { bv = d2; bi = code; }
    }
  }

  WV[w * 64 + lane] = bv;
  WI[w * 64 + lane] = bi;
  __syncthreads();
  if (t < 64) {
    const int pw = t >> 5;
    float fbv = FLT_MAX; int fbi = 0x7fffffff;
#pragma unroll
    for (int wcc = 0; wcc < 4; ++wcc)
#pragma unroll
      for (int hh = 0; hh < 2; ++hh) {
        const int li = (pw * 4 + wcc) * 64 + (t & 31) + hh * 32;
        const float v = WV[li];
        const int ii = WI[li];
        if (v < fbv || (v == fbv && ii < fbi)) { fbv = v; fbi = ii; }
      }
    out[OFF_A + n0 + t] = (float)fbi;
    IDX[t] = fbi;
  }
  __syncthreads();

  // ---- fused gather: emb[d][pix] = W[d][argmin[pix]] ----
  const int pix = t & 63;
  const int kidx = IDX[pix];
  for (int d = t >> 6; d < 512; d += 8)
    out[OFF_E + ((size_t)(b * 512 + d)) * 1024 + pixbase + pix] = Wc[(size_t)d * 512 + kidx];
}

// -------- decode via single-fp16 MFMA (q in (-0.04,0.04), err ~2e-5) --------
__global__ __launch_bounds__(512) void k_decmfma(const _Float16* __restrict__ wrow,
                                                 const _Float16* __restrict__ dwh,
                                                 const float* __restrict__ db,
                                                 float* __restrict__ out) {
  __shared__ __align__(16) _Float16 QB[2][4096];
  __shared__ int KIDX[128];
  const int t = threadIdx.x;
  const int w = t >> 6, lane = t & 63;
  const int pt = w & 3, mg = w >> 2;
  const int blk = blockIdx.x;
  const int b = blk >> 3;
  const int pixbase = (blk & 7) * 128;
  if (t < 128) KIDX[t] = (int)out[OFF_A + b * 1024 + pixbase + t];
  __syncthreads();
  const int pixS = t >> 2, slotS = t & 3;
  const _Float16* qsrc = wrow + (size_t)KIDX[pixS] * 512 + slotS * 8;
  const int ldsW = pixS * 32 + (slotS ^ ((pixS >> 1) & 3)) * 8;

  const _Float16* abp[3];
#pragma unroll
  for (int mt = 0; mt < 3; ++mt)
    abp[mt] = dwh + (size_t)((mg * 3 + mt) * 32 + (lane & 31)) * 512 + ((lane >> 5) << 3);

  const int brow = pt * 32 + (lane & 31);
  const int bsw = (brow >> 1) & 3;
  int boff[2];
#pragma unroll
  for (int ks = 0; ks < 2; ++ks)
    boff[ks] = brow * 32 + (((ks * 2 + (lane >> 5)) ^ bsw)) * 8;

  f32x16 acc[3];
#pragma unroll
  for (int mt = 0; mt < 3; ++mt) acc[mt] = (f32x16)(0.0f);
  f16x8 A[2][3][2];
  f16x8 qd[2];

  qd[0] = *(const f16x8*)(qsrc);
#pragma unroll
  for (int mt = 0; mt < 3; ++mt)
#pragma unroll
    for (int ks = 0; ks < 2; ++ks)
      A[0][mt][ks] = *(const f16x8*)(abp[mt] + ks * 16);
  *(f16x8*)&QB[0][ldsW] = qd[0];
  qd[1] = *(const f16x8*)(qsrc + 32);
  __syncthreads();

#pragma unroll
  for (int ch = 0; ch < 16; ++ch) {
    const int par = ch & 1;
    if (ch < 15) {
      *(f16x8*)&QB[par ^ 1][ldsW] = qd[(ch + 1) & 1];
#pragma unroll
      for (int mt = 0; mt < 3; ++mt)
#pragma unroll
        for (int ks = 0; ks < 2; ++ks)
          A[par ^ 1][mt][ks] = *(const f16x8*)(abp[mt] + (ch + 1) * 32 + ks * 16);
    }
    if (ch < 14) qd[ch & 1] = *(const f16x8*)(qsrc + (ch + 2) * 32);
    const f16x8 B0 = *(const f16x8*)&QB[par][boff[0]];
    const f16x8 B1 = *(const f16x8*)&QB[par][boff[1]];
#pragma unroll
    for (int mt = 0; mt < 3; ++mt) {
      acc[mt] = __builtin_amdgcn_mfma_f32_32x32x16_f16(A[par][mt][0], B0, acc[mt], 0, 0, 0);
      acc[mt] = __builtin_amdgcn_mfma_f32_32x32x16_f16(A[par][mt][1], B1, acc[mt], 0, 0, 0);
    }
    __syncthreads();
  }

  const float b0 = db[0], b1 = db[1], b2 = db[2];
  const int pix = pixbase + pt * 32 + (lane & 31);
  const int i = pix >> 5, j = pix & 31;
#pragma unroll
  for (int mt = 0; mt < 3; ++mt) {
    const int m0 = (mg * 3 + mt) * 32;
#pragma unroll
    for (int r = 0; r < 16; ++r) {
      const int m = m0 + (r & 3) + ((r >> 2) << 3) + ((lane >> 5) << 2);
      const int c = m >> 6, ki = (m >> 3) & 7, kj = m & 7;
      const float bias = (c == 0) ? b0 : ((c == 1) ? b1 : b2);
      out[(((size_t)b * 3 + c) * 256 + i * 8 + 7 - ki) * 256 + j * 8 + 7 - kj] = acc[mt][r] + bias;
    }
  }
}

// ---------------- decode fallback: fp32 VALU (if ws too small) --------------
__global__ __launch_bounds__(256) void k_decode(const float* __restrict__ dw,
                                                const float* __restrict__ db,
                                                float* out) {
  __shared__ __align__(16) float Qs[32][132];
  __shared__ __align__(16) float Ws3[32][68];
  const int n0 = blockIdx.x * 128;
  const int b = n0 / PIXB, pixbase = n0 % PIXB;
  const int mt = blockIdx.y;
  const int t = threadIdx.x;
  const int pg = t & 31, ck = t >> 5;
  float acc[4][8];
#pragma unroll
  for (int p = 0; p < 4; ++p)
#pragma unroll
    for (int k = 0; k < 8; ++k) acc[p][k] = 0.f;
  for (int dc = 0; dc < 16; ++dc) {
#pragma unroll
    for (int ii = 0; ii < 4; ++ii) {
      const int id = t + ii * 256;
      const int dd = id >> 5, p4 = id & 31;
      *reinterpret_cast<float4*>(&Qs[dd][p4 * 4]) =
        *reinterpret_cast<const float4*>(&out[OFF_E + ((size_t)b * 512 + dc * 32 + dd) * 1024 + pixbase + p4 * 4]);
    }
#pragma unroll
    for (int ii = 0; ii < 2; ++ii) {
      const int id = t + ii * 256;
      const int dd = id >> 4, m4 = id & 15;
      *reinterpret_cast<float4*>(&Ws3[dd][m4 * 4]) =
        *reinterpret_cast<const float4*>(&dw[(size_t)(dc * 32 + dd) * 192 + mt * 64 + m4 * 4]);
    }
    __syncthreads();
#pragma unroll
    for (int dd = 0; dd < 32; ++dd) {
      const float4 qv = *reinterpret_cast<const float4*>(&Qs[dd][pg * 4]);
      const float4 wa = *reinterpret_cast<const float4*>(&Ws3[dd][ck * 8]);
      const float4 wb = *reinterpret_cast<const float4*>(&Ws3[dd][ck * 8 + 4]);
      const float q[4] = {qv.x, qv.y, qv.z, qv.w};
      const float wv[8] = {wa.x, wa.y, wa.z, wa.w, wb.x, wb.y, wb.z, wb.w};
#pragma unroll
      for (int p = 0; p < 4; ++p)
#pragma unroll
        for (int k = 0; k < 8; ++k) acc[p][k] = fmaf(q[p], wv[k], acc[p][k]);
    }
    __syncthreads();
  }
  const int ckg = mt * 8 + ck;
  const int c = ckg >> 3, ki = ckg & 7;
  const float bias = db[c];
#pragma unroll
  for (int p = 0; p < 4; ++p) {
    const int pix = pixbase + pg * 4 + p;
    const int i = pix >> 5, j = pix & 31;
    const size_t base = (((size_t)b * 3 + c) * 256 + i * 8 + 7 - ki) * 256 + j * 8;
#pragma unroll
    for (int kj = 0; kj < 8; ++kj) out[base + 7 - kj] = acc[p][kj] + bias;
  }
}

extern "C" void kernel_launch(void* const* d_in, const int* in_sizes, int n_in,
                              void* d_out, int out_size, void* d_ws, size_t ws_size,
                              hipStream_t stream) {
  const float* x     = (const float*)d_in[0];
  const float* enc_w = (const float*)d_in[1];
  const float* enc_b = (const float*)d_in[2];
  const float* dec_w = (const float*)d_in[3];
  const float* dec_b = (const float*)d_in[4];
  const float* emb_w = (const float*)d_in[5];
  float* out = (float*)d_out;
  float* w2 = (float*)d_ws;                              // 2KB
  _Float16* wrow = (_Float16*)((char*)d_ws + 2048);      // 512KB
  _Float16* dwh  = (_Float16*)((char*)d_ws + 2048 + 524288);  // 192KB
  const int do_aux = (ws_size >= (size_t)(2048 + 524288 + 196608)) ? 1 : 0;
  _Float16* wq  = (_Float16*)d_out;                      // 1MB in recon region
  _Float16* aq  = (_Float16*)((char*)d_out + 2097152);   // 384KB in recon region
  // (scratch lives in recon region, fully overwritten by decode at the end)

  k_prep<<<122, 256, 0, stream>>>(emb_w, dec_w, enc_w, wq, w2, aq, wrow, dwh, do_aux);
  k_fused<<<512, 512, 0, stream>>>(x, aq, wq, enc_b, w2, emb_w, out);
  if (do_aux)
    k_decmfma<<<256, 512, 0, stream>>>(wrow, dwh, dec_b, out);
  else
    k_decode<<<dim3(256, 3), 256, 0, stream>>>(dec_w, dec_b, out);
}

// Round 19
// 185.414 us; speedup vs baseline: 1.0959x; 1.0959x over previous
//
#include <hip/hip_runtime.h>
#include <cfloat>

#define PIXB 1024
static const size_t OFF_Z = 6291456;   // recon = 32*3*256*256
static const size_t OFF_E = 23068672;  // OFF_Z + 32*512*32*32
static const size_t OFF_A = 39845888;  // OFF_E + 32*512*32*32

typedef __attribute__((address_space(1))) const unsigned int cg_u32;
typedef __attribute__((address_space(3))) unsigned int l_u32;
typedef _Float16 f16x8 __attribute__((ext_vector_type(8)));
typedef _Float16 f16x4 __attribute__((ext_vector_type(4)));
typedef float f32x16 __attribute__((ext_vector_type(16)));

#define SPLIT_SCALE 4096.0f
#define SPLIT_INV   (1.0f / 4096.0f)

#define GL16(srcp, dstp) __builtin_amdgcn_global_load_lds((cg_u32*)(srcp), (l_u32*)(dstp), 16, 0, 0)

// ---------------- prep: all weight-side tables ------------------------------
// wq QUARTER-chunk images (kslot-major): quarter qg(128 codes), chunk ch(32 d):
//   halves off = qg*131072 + ch*8192 + spl*4096 + kslot*1024 + cl*8
// 16KB per (qg,ch) image -> k_dist W ring 2x16KB fits 2 blocks/CU.
__global__ __launch_bounds__(256) void k_prep(const float* __restrict__ W,
                                              const float* __restrict__ dw,
                                              const float* __restrict__ ew,
                                              _Float16* __restrict__ wq,
                                              float* __restrict__ w2,
                                              _Float16* __restrict__ aq,
                                              _Float16* __restrict__ wrow,
                                              _Float16* __restrict__ dwh,
                                              int do_aux) {
  const int t = threadIdx.x;
  const int bx = blockIdx.x;
  __shared__ float T[64][65];
  __shared__ float T2[128][65];
  if (bx < 32) {
    __shared__ float TS[32][260];
    const int cp = bx >> 4, ch = bx & 15;
#pragma unroll
    for (int i = 0; i < 32; ++i)
      TS[i][t] = W[(size_t)(ch * 32 + i) * 512 + cp * 256 + t];
    __syncthreads();
#pragma unroll
    for (int j = 0; j < 4; ++j) {
      const int u = j * 256 + t;
      const int c = u >> 2, kslot = u & 3;
      f16x8 h, l;
#pragma unroll
      for (int jj = 0; jj < 8; ++jj) {
        const float v = TS[kslot * 8 + jj][c];
        const _Float16 hh = (_Float16)v;
        h[jj] = hh;
        l[jj] = (_Float16)((v - (float)hh) * SPLIT_SCALE);
      }
      const int qg = cp * 2 + (c >> 7);
      const int cl = c & 127;
      _Float16* base = wq + qg * 131072 + ch * 8192 + kslot * 1024 + cl * 8;
      *(f16x8*)(base) = h;            // spl 0
      *(f16x8*)(base + 4096) = l;     // spl 1
    }
    return;
  }
  if (bx < 34) {
    const int k = (bx - 32) * 256 + t;
    float acc = 0.f;
    for (int d = 0; d < 512; ++d) { const float v = W[(size_t)d * 512 + k]; acc = fmaf(v, v, acc); }
    w2[k] = acc;
    return;
  }
  if (bx < 46) {                 // aq: enc_w [c][192] -> chunk images
    const int ch = bx - 34;
#pragma unroll
    for (int cc = 0; cc < 2; ++cc) {
      const int c = cc * 256 + t;
      const float* src = ew + (size_t)c * 192 + ch * 16;
#pragma unroll
      for (int slot = 0; slot < 2; ++slot) {
        f16x8 h, l;
#pragma unroll
        for (int j = 0; j < 8; ++j) {
          const float v = src[slot * 8 + j];
          const _Float16 hh = (_Float16)v;
          h[j] = hh;
          l[j] = (_Float16)((v - (float)hh) * SPLIT_SCALE);
        }
        const int se = slot ^ ((c >> 2) & 1);
        _Float16* dst = aq + (size_t)ch * 16384 + c * 16 + se * 8;
        *(f16x8*)dst = h;
        *(f16x8*)(dst + 8192) = l;
      }
    }
    return;
  }
  if (!do_aux) return;
  if (bx < 110) {                // wrow: transpose W [d][c] -> fp16 [c][d]
    const int id = bx - 46;
    const int c0 = (id & 7) * 64, d0 = (id >> 3) * 64;
#pragma unroll
    for (int i = 0; i < 16; ++i) {
      const int dl = i * 4 + (t >> 6);
      T[dl][t & 63] = W[(size_t)(d0 + dl) * 512 + c0 + (t & 63)];
    }
    __syncthreads();
#pragma unroll
    for (int i = 0; i < 16; ++i) {
      const int cl = i * 4 + (t >> 6);
      const int dl = t & 63;
      wrow[(size_t)(c0 + cl) * 512 + d0 + dl] = (_Float16)T[dl][cl];
    }
    return;
  }
  {                              // dwh: transpose dec_w [d][m] -> fp16 [m][d]
    const int id = bx - 110;
    const int m0 = (id % 3) * 64, d0 = (id / 3) * 128;
#pragma unroll
    for (int i = 0; i < 32; ++i) {
      const int idx = i * 256 + t;
      const int dl = idx >> 6, ml = idx & 63;
      T2[dl][ml] = dw[(size_t)(d0 + dl) * 192 + m0 + ml];
    }
    __syncthreads();
#pragma unroll
    for (int i = 0; i < 32; ++i) {
      const int idx = i * 256 + t;
      const int ml = idx >> 7, dl = idx & 127;
      dwh[(size_t)(m0 + ml) * 512 + d0 + dl] = (_Float16)T2[dl][ml];
    }
  }
}

// -------- encode via MFMA (fp16 2-split, 3 products), counted-vmcnt ---------
__global__ __launch_bounds__(512) void k_encmfma(const float* __restrict__ x,
                                                 const _Float16* __restrict__ aq,
                                                 const float* __restrict__ eb,
                                                 float* __restrict__ out) {
  __shared__ __align__(16) unsigned char CB[131072];  // A 3x32KB | B 4x8KB
  __shared__ float ebL[512];
  const int t = threadIdx.x;
  ebL[t] = eb[t];
  const int w = t >> 6, lane = t & 63;
  const int wc = w & 3, wp = w >> 2;
  const int n0 = blockIdx.x * 64;
  const int b = n0 >> 10, pixbase = n0 & 1023;
  const int i0 = pixbase >> 5;
  const int row = lane & 31, hi = lane >> 5;

  int ab[4];
#pragma unroll
  for (int ct = 0; ct < 4; ++ct) {
    const int c = wc * 128 + ct * 32 + row;
    ab[ct] = c * 32 + ((hi ^ ((c >> 2) & 1)) << 4);
  }
  const int u = t & 255, srow = u >> 6, vsl = u & 63;
  const int csrc = vsl ^ ((vsl >> 3) & 1);
  const float* xb = x + ((size_t)b * 3 * 256 + (i0 + (srow >> 1)) * 8 + (srow & 1)) * 256 + csrc * 4;
  const int bv0 = (((2 * row) ^ ((row >> 2) & 1)) << 4);
  const int bv1 = (((2 * row + 1) ^ ((row >> 2) & 1)) << 4);
  const int brb = wp * 4096 + (wp * 2 + hi) * 1024;

  f32x16 accA[4], accB[4];
#pragma unroll
  for (int ct = 0; ct < 4; ++ct) { accA[ct] = (f32x16)(0.0f); accB[ct] = (f32x16)(0.0f); }

#define STAGE_A(chv) { const _Float16* as_ = aq + (size_t)(chv) * 16384 + t * 8;            \
    char* ad_ = (char*)CB + ((chv) % 3) * 32768 + t * 16;                                   \
    GL16(as_, ad_); GL16(as_ + 4096, ad_ + 8192);                                           \
    GL16(as_ + 8192, ad_ + 16384); GL16(as_ + 12288, ad_ + 24576); }
#define STAGE_B(chv) GL16(xb + (((chv) >> 2) * 65536 + ((chv) & 3) * 512),                  \
                          (char*)CB + 98304 + (((chv) & 3)) * 8192 + t * 16)
#define ECOMP(chv)                                                                          \
  { const char* abuf = (const char*)CB + ((chv) % 3) * 32768;                               \
    const char* bbuf = (const char*)CB + 98304 + ((chv) & 3) * 8192 + brb;                  \
    const float4 xa = *(const float4*)(bbuf + bv0);                                         \
    const float4 xc = *(const float4*)(bbuf + bv1);                                         \
    const float xs[8] = {xa.x, xa.y, xa.z, xa.w, xc.x, xc.y, xc.z, xc.w};                   \
    f16x8 Bh, Bl;                                                                           \
    _Pragma("unroll") for (int q = 0; q < 8; ++q) {                                         \
      const _Float16 hh = (_Float16)xs[q];                                                  \
      Bh[q] = hh; Bl[q] = (_Float16)((xs[q] - (float)hh) * SPLIT_SCALE); }                  \
    __builtin_amdgcn_s_setprio(1);                                                          \
    _Pragma("unroll") for (int ct_ = 0; ct_ < 4; ++ct_) {                                   \
      const f16x8 Ah = *(const f16x8*)(abuf + ab[ct_]);                                     \
      const f16x8 Al = *(const f16x8*)(abuf + 16384 + ab[ct_]);                             \
      accA[ct_] = __builtin_amdgcn_mfma_f32_32x32x16_f16(Ah, Bh, accA[ct_], 0, 0, 0);       \
      accB[ct_] = __builtin_amdgcn_mfma_f32_32x32x16_f16(Ah, Bl, accB[ct_], 0, 0, 0);       \
      accB[ct_] = __builtin_amdgcn_mfma_f32_32x32x16_f16(Al, Bh, accB[ct_], 0, 0, 0); }     \
    __builtin_amdgcn_s_setprio(0); }
#define EPHASE(chv, waitlit)                                                                \
  { asm volatile("s_waitcnt vmcnt(" #waitlit ")" ::: "memory");                             \
    __builtin_amdgcn_sched_barrier(0);                                                      \
    __builtin_amdgcn_s_barrier();                                                           \
    ECOMP(chv);                                                                             \
    __builtin_amdgcn_s_barrier(); }

  STAGE_A(0); STAGE_B(0);
  STAGE_A(1); STAGE_B(1);
  STAGE_B(2);
#pragma unroll 1
  for (int ch = 0; ch < 9; ++ch) {
    STAGE_A(ch + 2);
    STAGE_B(ch + 3);
    EPHASE(ch, 11);
  }
  STAGE_A(11);
  EPHASE(9, 10);
  EPHASE(10, 5);
  EPHASE(11, 0);
#undef STAGE_A
#undef STAGE_B
#undef ECOMP
#undef EPHASE

  const int pl = wp * 32 + row;
#pragma unroll
  for (int ct = 0; ct < 4; ++ct) {
#pragma unroll
    for (int r = 0; r < 16; ++r) {
      const int c = wc * 128 + ct * 32 + (r & 3) + ((r >> 2) << 3) + (hi << 2);
      out[OFF_Z + ((size_t)(b * 512 + c)) * 1024 + pixbase + pl] =
          fmaf(accB[ct][r], SPLIT_INV, accA[ct][r]) + ebL[c];
    }
  }
}

// -------- distance partials: 128 codes/block, 2 blocks/CU --------------------
// Quartered code range (grid 2048, q=swz&3): LDS = W 2x16K + raw-z 3x8K +
// split 2x8K = 72KB -> 2 blocks/CU; co-resident block fills vmcnt/barrier
// stalls. XCD swizzle co-locates a tile's 4 quarters on one XCD. 3 loads/
// thread/chunk; kslot-major layouts keep all LDS ops <=2-way. Accumulator
// sequence bit-identical to rounds 10-15.
__global__ __launch_bounds__(512) void k_dist(const _Float16* __restrict__ wq,
                                              const float* __restrict__ w2ws,
                                              const float* __restrict__ zin,
                                              float* __restrict__ pv,
                                              int* __restrict__ pi) {
  __shared__ __align__(16) unsigned char CB[73728];  // W 2x16K | raw 3x8K | split 2x8K
  __shared__ float WV[512];
  __shared__ int   WI[512];
  const int t = threadIdx.x;
  const int w = t >> 6, lane = t & 63;
  const int wc = w & 3, wp = w >> 2;
  const int bid0 = blockIdx.x;
  const int swz = (bid0 & 7) * 256 + (bid0 >> 3);   // XCD-chunked, bijective (2048%8==0)
  const int tile = swz >> 2, q = swz & 3;
  const int n0 = tile * 64;
  const int b = n0 >> 10, pixbase = n0 & 1023;
  const int row = lane & 31, hi = lane >> 5;
  const int pl = wp * 32 + row;

  int abase[2];
#pragma unroll
  for (int ks = 0; ks < 2; ++ks)
    abase[ks] = (2 * ks + hi) * 2048 + (wc * 32 + row) * 16;
  const int swpl = (pl ^ ((pl >> 3) & 3)) * 16;
  const int swln = (lane ^ ((lane >> 3) & 3)) * 16;
  const int twH = (w >> 1) * 1024 + swln + (w & 1) * 8;
  const float* zsrc = zin + OFF_Z + ((size_t)(b * 512 + (t >> 4))) * 1024 + pixbase + (t & 15) * 4;
  const _Float16* wqb = wq + q * 131072;

#define STAGE_W(chv)                                                             \
  { const _Float16* ws_ = wqb + (chv) * 8192 + t * 8;                            \
    char* wd_ = (char*)CB + ((chv) & 1) * 16384 + t * 16;                        \
    GL16(ws_, wd_); GL16(ws_ + 4096, wd_ + 8192); }
#define STAGE_Z(chv)                                                             \
  GL16(zsrc + (size_t)(chv) * 32768,                                             \
       (char*)CB + 32768 + ((chv) % 3) * 8192 + t * 16)
#define TRANSPOSE(chv)                                                           \
  { const char* rb_ = (const char*)CB + 32768 + ((chv) % 3) * 8192;              \
    char* sb_ = (char*)CB + 57344 + ((chv) & 1) * 8192;                          \
    f16x4 hv_, lv_;                                                              \
    _Pragma("unroll") for (int j_ = 0; j_ < 4; ++j_) {                           \
      const float f_ = *(const float*)(rb_ + (4 * w + j_) * 256 + lane * 4);     \
      const _Float16 hh_ = (_Float16)f_;                                         \
      hv_[j_] = hh_;                                                             \
      lv_[j_] = (_Float16)((f_ - (float)hh_) * SPLIT_SCALE); }                   \
    *(f16x4*)(sb_ + twH) = hv_;                                                  \
    *(f16x4*)(sb_ + 4096 + twH) = lv_; }
#define COMPUTE(chv)                                                             \
  { const char* wb_ = (const char*)CB + ((chv) & 1) * 16384;                     \
    const char* zb_ = (const char*)CB + 57344 + ((chv) & 1) * 8192;              \
    const f16x8 Bh0 = *(const f16x8*)(zb_ + hi * 1024 + swpl);                   \
    const f16x8 Bh1 = *(const f16x8*)(zb_ + (2 + hi) * 1024 + swpl);             \
    const f16x8 Bl0 = *(const f16x8*)(zb_ + 4096 + hi * 1024 + swpl);            \
    const f16x8 Bl1 = *(const f16x8*)(zb_ + 4096 + (2 + hi) * 1024 + swpl);      \
    const f16x8 Ah0 = *(const f16x8*)(wb_ + abase[0]);                           \
    const f16x8 Al0 = *(const f16x8*)(wb_ + 8192 + abase[0]);                    \
    const f16x8 Ah1 = *(const f16x8*)(wb_ + abase[1]);                           \
    const f16x8 Al1 = *(const f16x8*)(wb_ + 8192 + abase[1]);                    \
    __builtin_amdgcn_s_setprio(1);                                               \
    accA = __builtin_amdgcn_mfma_f32_32x32x16_f16(Ah0, Bh0, accA, 0, 0, 0);      \
    accB = __builtin_amdgcn_mfma_f32_32x32x16_f16(Ah0, Bl0, accB, 0, 0, 0);      \
    accB = __builtin_amdgcn_mfma_f32_32x32x16_f16(Al0, Bh0, accB, 0, 0, 0);      \
    accA = __builtin_amdgcn_mfma_f32_32x32x16_f16(Ah1, Bh1, accA, 0, 0, 0);      \
    accB = __builtin_amdgcn_mfma_f32_32x32x16_f16(Ah1, Bl1, accB, 0, 0, 0);      \
    accB = __builtin_amdgcn_mfma_f32_32x32x16_f16(Al1, Bh1, accB, 0, 0, 0);      \
    __builtin_amdgcn_s_setprio(0); }
#define LGKM0                                                                    \
  { asm volatile("s_waitcnt lgkmcnt(0)" ::: "memory");                           \
    __builtin_amdgcn_sched_barrier(0); }
#define PHASE_T(chv, waitlit)                                                    \
  { asm volatile("s_waitcnt vmcnt(" #waitlit ")" ::: "memory");                  \
    __builtin_amdgcn_sched_barrier(0);                                           \
    __builtin_amdgcn_s_barrier();                                                \
    TRANSPOSE((chv) + 1);                                                        \
    COMPUTE(chv);                                                                \
    LGKM0;                                                                       \
    __builtin_amdgcn_s_barrier(); }
#define PHASE_F(chv, waitlit)                                                    \
  { asm volatile("s_waitcnt vmcnt(" #waitlit ")" ::: "memory");                  \
    __builtin_amdgcn_sched_barrier(0);                                           \
    __builtin_amdgcn_s_barrier();                                                \
    COMPUTE(chv);                                                                \
    LGKM0;                                                                       \
    __builtin_amdgcn_s_barrier(); }

  f32x16 accA = (f32x16)(0.0f), accB = (f32x16)(0.0f);

  // prologue: W(0)[#1-2], z(0)[#3], z(1)[#4], z(2)[#5]
  STAGE_W(0);
  STAGE_Z(0); STAGE_Z(1); STAGE_Z(2);
  asm volatile("s_waitcnt vmcnt(2)" ::: "memory");   // z(0) arrived
  __builtin_amdgcn_sched_barrier(0);
  __builtin_amdgcn_s_barrier();
  TRANSPOSE(0);
  LGKM0;
  __builtin_amdgcn_s_barrier();
#pragma unroll 1
  for (int ch = 0; ch < 13; ++ch) {
    STAGE_W(ch + 1);
    STAGE_Z(ch + 3);
    PHASE_T(ch, 4);
  }
  STAGE_W(14);
  PHASE_T(13, 3);
  STAGE_W(15);
  PHASE_T(14, 2);
  PHASE_F(15, 0);

  // ---- d2 + per-thread argmin over this thread's 16 codes ----
  float bv = FLT_MAX; int bi = 0x7fffffff;
#pragma unroll
  for (int r = 0; r < 16; ++r) {
    const int code = (q << 7) + wc * 32 + ((r & 3) + ((r >> 2) << 3) + (hi << 2));
    const float zw = fmaf(accB[r], SPLIT_INV, accA[r]);
    const float d2 = fmaf(-2.f, zw, w2ws[code]);
    if (d2 < bv || (d2 == bv && code < bi)) { bv = d2; bi = code; }
  }
#undef STAGE_W
#undef STAGE_Z
#undef TRANSPOSE
#undef COMPUTE
#undef LGKM0
#undef PHASE_T
#undef PHASE_F

  WV[w * 64 + lane] = bv;
  WI[w * 64 + lane] = bi;
  __syncthreads();
  if (t < 64) {
    const int pw = t >> 5;
    float fbv = FLT_MAX; int fbi = 0x7fffffff;
#pragma unroll
    for (int wcc = 0; wcc < 4; ++wcc)
#pragma unroll
      for (int hh = 0; hh < 2; ++hh) {
        const int li = (pw * 4 + wcc) * 64 + (t & 31) + hh * 32;
        const float v = WV[li];
        const int ii = WI[li];
        if (v < fbv || (v == fbv && ii < fbi)) { fbv = v; fbi = ii; }
      }
    pv[q * 32768 + n0 + t] = fbv;
    pi[q * 32768 + n0 + t] = fbi;
  }
}

// -------- merge 4 quarter-partials + argmin write + emb gather --------------
__global__ __launch_bounds__(512) void k_merge(const float* __restrict__ Wc,
                                               const float* __restrict__ pv,
                                               const int* __restrict__ pi,
                                               float* __restrict__ out) {
  __shared__ int IDX[64];
  const int t = threadIdx.x;
  const int n0 = blockIdx.x * 64;
  const int b = n0 >> 10, pixbase = n0 & 1023;
  if (t < 64) {
    float fbv = pv[n0 + t]; int fbi = pi[n0 + t];
#pragma unroll
    for (int q = 1; q < 4; ++q) {
      const float v = pv[q * 32768 + n0 + t];
      const int ii = pi[q * 32768 + n0 + t];
      if (v < fbv || (v == fbv && ii < fbi)) { fbv = v; fbi = ii; }
    }
    out[OFF_A + n0 + t] = (float)fbi;
    IDX[t] = fbi;
  }
  __syncthreads();
  const int pix = t & 63;
  const int kidx = IDX[pix];
  for (int d = t >> 6; d < 512; d += 8)
    out[OFF_E + ((size_t)(b * 512 + d)) * 1024 + pixbase + pix] = Wc[(size_t)d * 512 + kidx];
}

// -------- decode via single-fp16 MFMA (q in (-0.04,0.04), err ~2e-5) --------
__global__ __launch_bounds__(512) void k_decmfma(const _Float16* __restrict__ wrow,
                                                 const _Float16* __restrict__ dwh,
                                                 const float* __restrict__ db,
                                                 float* __restrict__ out) {
  __shared__ __align__(16) _Float16 QB[2][4096];
  __shared__ int KIDX[128];
  const int t = threadIdx.x;
  const int w = t >> 6, lane = t & 63;
  const int pt = w & 3, mg = w >> 2;
  const int blk = blockIdx.x;
  const int b = blk >> 3;
  const int pixbase = (blk & 7) * 128;
  if (t < 128) KIDX[t] = (int)out[OFF_A + b * 1024 + pixbase + t];
  __syncthreads();
  const int pixS = t >> 2, slotS = t & 3;
  const _Float16* qsrc = wrow + (size_t)KIDX[pixS] * 512 + slotS * 8;
  const int ldsW = pixS * 32 + (slotS ^ ((pixS >> 1) & 3)) * 8;

  const _Float16* abp[3];
#pragma unroll
  for (int mt = 0; mt < 3; ++mt)
    abp[mt] = dwh + (size_t)((mg * 3 + mt) * 32 + (lane & 31)) * 512 + ((lane >> 5) << 3);

  const int brow = pt * 32 + (lane & 31);
  const int bsw = (brow >> 1) & 3;
  int boff[2];
#pragma unroll
  for (int ks = 0; ks < 2; ++ks)
    boff[ks] = brow * 32 + (((ks * 2 + (lane >> 5)) ^ bsw)) * 8;

  f32x16 acc[3];
#pragma unroll
  for (int mt = 0; mt < 3; ++mt) acc[mt] = (f32x16)(0.0f);
  f16x8 A[2][3][2];
  f16x8 qd[2];

  qd[0] = *(const f16x8*)(qsrc);
#pragma unroll
  for (int mt = 0; mt < 3; ++mt)
#pragma unroll
    for (int ks = 0; ks < 2; ++ks)
      A[0][mt][ks] = *(const f16x8*)(abp[mt] + ks * 16);
  *(f16x8*)&QB[0][ldsW] = qd[0];
  qd[1] = *(const f16x8*)(qsrc + 32);
  __syncthreads();

#pragma unroll
  for (int ch = 0; ch < 16; ++ch) {
    const int par = ch & 1;
    if (ch < 15) {
      *(f16x8*)&QB[par ^ 1][ldsW] = qd[(ch + 1) & 1];
#pragma unroll
      for (int mt = 0; mt < 3; ++mt)
#pragma unroll
        for (int ks = 0; ks < 2; ++ks)
          A[par ^ 1][mt][ks] = *(const f16x8*)(abp[mt] + (ch + 1) * 32 + ks * 16);
    }
    if (ch < 14) qd[ch & 1] = *(const f16x8*)(qsrc + (ch + 2) * 32);
    const f16x8 B0 = *(const f16x8*)&QB[par][boff[0]];
    const f16x8 B1 = *(const f16x8*)&QB[par][boff[1]];
#pragma unroll
    for (int mt = 0; mt < 3; ++mt) {
      acc[mt] = __builtin_amdgcn_mfma_f32_32x32x16_f16(A[par][mt][0], B0, acc[mt], 0, 0, 0);
      acc[mt] = __builtin_amdgcn_mfma_f32_32x32x16_f16(A[par][mt][1], B1, acc[mt], 0, 0, 0);
    }
    __syncthreads();
  }

  const float b0 = db[0], b1 = db[1], b2 = db[2];
  const int pix = pixbase + pt * 32 + (lane & 31);
  const int i = pix >> 5, j = pix & 31;
#pragma unroll
  for (int mt = 0; mt < 3; ++mt) {
    const int m0 = (mg * 3 + mt) * 32;
#pragma unroll
    for (int r = 0; r < 16; ++r) {
      const int m = m0 + (r & 3) + ((r >> 2) << 3) + ((lane >> 5) << 2);
      const int c = m >> 6, ki = (m >> 3) & 7, kj = m & 7;
      const float bias = (c == 0) ? b0 : ((c == 1) ? b1 : b2);
      out[(((size_t)b * 3 + c) * 256 + i * 8 + 7 - ki) * 256 + j * 8 + 7 - kj] = acc[mt][r] + bias;
    }
  }
}

// ---------------- decode fallback: fp32 VALU (if ws too small) --------------
__global__ __launch_bounds__(256) void k_decode(const float* __restrict__ dw,
                                                const float* __restrict__ db,
                                                float* out) {
  __shared__ __align__(16) float Qs[32][132];
  __shared__ __align__(16) float Ws3[32][68];
  const int n0 = blockIdx.x * 128;
  const int b = n0 / PIXB, pixbase = n0 % PIXB;
  const int mt = blockIdx.y;
  const int t = threadIdx.x;
  const int pg = t & 31, ck = t >> 5;
  float acc[4][8];
#pragma unroll
  for (int p = 0; p < 4; ++p)
#pragma unroll
    for (int k = 0; k < 8; ++k) acc[p][k] = 0.f;
  for (int dc = 0; dc < 16; ++dc) {
#pragma unroll
    for (int ii = 0; ii < 4; ++ii) {
      const int id = t + ii * 256;
      const int dd = id >> 5, p4 = id & 31;
      *reinterpret_cast<float4*>(&Qs[dd][p4 * 4]) =
        *reinterpret_cast<const float4*>(&out[OFF_E + ((size_t)b * 512 + dc * 32 + dd) * 1024 + pixbase + p4 * 4]);
    }
#pragma unroll
    for (int ii = 0; ii < 2; ++ii) {
      const int id = t + ii * 256;
      const int dd = id >> 4, m4 = id & 15;
      *reinterpret_cast<float4*>(&Ws3[dd][m4 * 4]) =
        *reinterpret_cast<const float4*>(&dw[(size_t)(dc * 32 + dd) * 192 + mt * 64 + m4 * 4]);
    }
    __syncthreads();
#pragma unroll
    for (int dd = 0; dd < 32; ++dd) {
      const float4 qv = *reinterpret_cast<const float4*>(&Qs[dd][pg * 4]);
      const float4 wa = *reinterpret_cast<const float4*>(&Ws3[dd][ck * 8]);
      const float4 wb = *reinterpret_cast<const float4*>(&Ws3[dd][ck * 8 + 4]);
      const float q[4] = {qv.x, qv.y, qv.z, qv.w};
      const float wv[8] = {wa.x, wa.y, wa.z, wa.w, wb.x, wb.y, wb.z, wb.w};
#pragma unroll
      for (int p = 0; p < 4; ++p)
#pragma unroll
        for (int k = 0; k < 8; ++k) acc[p][k] = fmaf(q[p], wv[k], acc[p][k]);
    }
    __syncthreads();
  }
  const int ckg = mt * 8 + ck;
  const int c = ckg >> 3, ki = ckg & 7;
  const float bias = db[c];
#pragma unroll
  for (int p = 0; p < 4; ++p) {
    const int pix = pixbase + pg * 4 + p;
    const int i = pix >> 5, j = pix & 31;
    const size_t base = (((size_t)b * 3 + c) * 256 + i * 8 + 7 - ki) * 256 + j * 8;
#pragma unroll
    for (int kj = 0; kj < 8; ++kj) out[base + 7 - kj] = acc[p][kj] + bias;
  }
}

extern "C" void kernel_launch(void* const* d_in, const int* in_sizes, int n_in,
                              void* d_out, int out_size, void* d_ws, size_t ws_size,
                              hipStream_t stream) {
  const float* x     = (const float*)d_in[0];
  const float* enc_w = (const float*)d_in[1];
  const float* enc_b = (const float*)d_in[2];
  const float* dec_w = (const float*)d_in[3];
  const float* dec_b = (const float*)d_in[4];
  const float* emb_w = (const float*)d_in[5];
  float* out = (float*)d_out;
  float* w2 = (float*)d_ws;                              // 2KB
  _Float16* wrow = (_Float16*)((char*)d_ws + 2048);      // 512KB
  _Float16* dwh  = (_Float16*)((char*)d_ws + 2048 + 524288);  // 192KB
  const int do_aux = (ws_size >= (size_t)(2048 + 524288 + 196608)) ? 1 : 0;
  _Float16* wq  = (_Float16*)d_out;                      // 1MB in recon region
  _Float16* aq  = (_Float16*)((char*)d_out + 2097152);   // 384KB in recon region
  float* pv = (float*)((char*)d_out + 4194304);          // 512KB partial values
  int*   pi = (int*)((char*)d_out + 4194304 + 524288);   // 512KB partial indices
  // (all scratch in recon region < 25MB; recon fully overwritten by decode)

  k_prep<<<122, 256, 0, stream>>>(emb_w, dec_w, enc_w, wq, w2, aq, wrow, dwh, do_aux);
  k_encmfma<<<512, 512, 0, stream>>>(x, aq, enc_b, out);
  k_dist<<<2048, 512, 0, stream>>>(wq, w2, out, pv, pi);
  k_merge<<<512, 512, 0, stream>>>(emb_w, pv, pi, out);
  if (do_aux)
    k_decmfma<<<256, 512, 0, stream>>>(wrow, dwh, dec_b, out);
  else
    k_decode<<<dim3(256, 3), 256, 0, stream>>>(dec_w, dec_b, out);
}